// Round 14
// baseline (326.751 us; speedup 1.0000x reference)
//
#include <hip/hip_runtime.h>
#include <stdint.h>

#define DIM 1024
#define NH  16
#define HD  64
#define BB  4
#define TT  4096
#define BT  (BB*TT)   // 16384
#define NC  32        // number of chunks
#define CL  128       // chunk length

typedef __bf16 bf16x8 __attribute__((ext_vector_type(8)));
typedef float  f32x4  __attribute__((ext_vector_type(4)));

__device__ __forceinline__ float bfu(unsigned int u) {
    return __uint_as_float((u & 0xffffu) << 16);
}
__device__ __forceinline__ unsigned short f2bf(float f) {
    unsigned int u = __float_as_uint(f);
    u += 0x7fffu + ((u >> 16) & 1u);
    return (unsigned short)(u >> 16);
}

__device__ __forceinline__ void gload16(const void* g, void* lds) {
    __builtin_amdgcn_global_load_lds((__attribute__((address_space(1))) void*)g,
                                     (__attribute__((address_space(3))) void*)lds,
                                     16, 0, 0);
}

// ---------------- elementwise converters ----------------

__global__ __launch_bounds__(256) void conv_x_kernel(
    const float* __restrict__ x, const float* __restrict__ tmix,
    unsigned short* __restrict__ xx)
{
    int gid = blockIdx.x * 256 + threadIdx.x;          // 4 elems per thread
    float4 xv = ((const float4*)x)[gid];
    float4 tv = ((const float4*)tmix)[gid & 255];
    uint2 o;
    o.x = (unsigned)f2bf(xv.x * tv.x) | ((unsigned)f2bf(xv.y * tv.y) << 16);
    o.y = (unsigned)f2bf(xv.z * tv.z) | ((unsigned)f2bf(xv.w * tv.w) << 16);
    ((uint2*)xx)[gid] = o;
}

__global__ __launch_bounds__(256) void conv_w_kernel(
    const float* __restrict__ Wk, const float* __restrict__ Wv,
    const float* __restrict__ Wr, const float* __restrict__ Wg,
    const float* __restrict__ Wo,
    unsigned short* __restrict__ wcat, unsigned short* __restrict__ wob)
{
    int gid = blockIdx.x * 256 + threadIdx.x;          // 0..1310719
    size_t idx = (size_t)gid * 4;
    float4 v;
    unsigned short* dst;
    if (idx < 4194304) {
        int p = (int)(idx >> 20);
        size_t loc = idx & 1048575;
        const float* src = (p == 0) ? Wk : (p == 1) ? Wv : (p == 2) ? Wr : Wg;
        v = ((const float4*)src)[loc >> 2];
        dst = wcat + idx;
    } else {
        size_t loc = idx - 4194304;
        v = ((const float4*)Wo)[loc >> 2];
        dst = wob + loc;
    }
    uint2 o;
    o.x = (unsigned)f2bf(v.x) | ((unsigned)f2bf(v.y) << 16);
    o.y = (unsigned)f2bf(v.z) | ((unsigned)f2bf(v.w) << 16);
    *(uint2*)dst = o;
}

// ============ 256x256 8-phase bf16 MFMA GEMM (A[M,K] * B[N,K]^T) ============
// (R7/R9-proven schedule; R12 2D-XCD map. EPI==0: LDS-repack coalesced epi.)

#define MFMAQ(accb, av, bv)                                                    \
    _Pragma("unroll") for (int mi_ = 0; mi_ < 4; ++mi_)                        \
    _Pragma("unroll") for (int ni_ = 0; ni_ < 4; ++ni_)                        \
        acc[(accb)+mi_][ni_] = __builtin_amdgcn_mfma_f32_16x16x32_bf16(        \
            av[mi_], bv[ni_], acc[(accb)+mi_][ni_], 0, 0, 0);

#define LDA4(dst, mib, kh, bi)                                                 \
    _Pragma("unroll") for (int q_ = 0; q_ < 4; ++q_)                           \
        dst[q_] = *(const bf16x8*)&As[bi][(kh)*8192 + (arow + ((mib)+q_)*16)*32 + kxu];

#define LDB4(dst, kh, bi)                                                      \
    _Pragma("unroll") for (int q_ = 0; q_ < 4; ++q_)                           \
        dst[q_] = *(const bf16x8*)&Bs[bi][(kh)*8192 + (brow + q_*16)*32 + kxu];

#define STAGE_A(nb, kh, k0e) do {                                              \
    gload16(Asrc0 + (k0e) + (kh)*32, &As[nb][(kh)*8192 + d0]);                 \
    gload16(Asrc1 + (k0e) + (kh)*32, &As[nb][(kh)*8192 + d1]); } while (0)

#define STAGE_B(nb, kh, k0e) do {                                              \
    gload16(Bsrc0 + (k0e) + (kh)*32, &Bs[nb][(kh)*8192 + d0]);                 \
    gload16(Bsrc1 + (k0e) + (kh)*32, &Bs[nb][(kh)*8192 + d1]); } while (0)

#define SBAR()  __builtin_amdgcn_s_barrier()
#define SCHED0() __builtin_amdgcn_sched_barrier(0)
#define WAIT_LGKM0() asm volatile("s_waitcnt lgkmcnt(0)" ::: "memory")
#define WAIT_VM(n)   asm volatile("s_waitcnt vmcnt(" #n ")" ::: "memory")

template<int EPI>
__global__ __launch_bounds__(512, 2) void gemm256(
    const unsigned short* __restrict__ A, const unsigned short* __restrict__ B,
    float* __restrict__ C, int M, int N, int K,
    unsigned short* __restrict__ kb, unsigned short* __restrict__ vb,
    unsigned short* __restrict__ rb, unsigned short* __restrict__ gb)
{
    __shared__ unsigned short As[2][16384];   // 64 KB
    __shared__ unsigned short Bs[2][16384];   // 64 KB

    const int tid  = threadIdx.x;
    const int lane = tid & 63;
    const int wv   = tid >> 6;
    const int wr   = wv >> 2;      // 0..1  (M)
    const int wc   = wv & 3;       // 0..3  (N)
    const int lrow = lane & 15;
    const int kseg = lane >> 4;    // 0..3

    const int bid = blockIdx.x;
    int bx, by;
    if (EPI == 0) {
        // gemm1: 1024 blocks = 64M x 16N. XCD x owns M-rows [8x,8x+8), all N,
        // traversed in 4x4 sub-tiles (R12: FETCH 147->98 MB, at analytic floor).
        const int xcd = bid & 7, q = bid >> 3;         // q in [0,128)
        const int dm = (q >> 2) & 3, dn = q & 3;
        const int sn = (q >> 4) & 3, sm = q >> 6;      // sm in [0,2)
        by = xcd * 8 + sm * 4 + dm;
        bx = sn * 4 + dn;
    } else {
        const int nwg = gridDim.x;
        const int cpx = nwg >> 3;
        const int wg  = (bid & 7) * cpx + (bid >> 3);
        const int nbx = N >> 8;
        bx = wg % nbx; by = wg / nbx;
    }
    const size_t bm = (size_t)by * 256, bn = (size_t)bx * 256;

    const int r0 = tid >> 2;
    const int c0 = (tid & 3) ^ (((tid >> 5) & 1) << 1);
    const int r1 = (512 + tid) >> 2;
    const int c1 = (tid & 3) ^ ((((512 + tid) >> 5) & 1) << 1);
    const unsigned short* Asrc0 = A + (bm + r0) * (size_t)K + c0 * 8;
    const unsigned short* Asrc1 = A + (bm + r1) * (size_t)K + c1 * 8;
    const unsigned short* Bsrc0 = B + (bn + r0) * (size_t)K + c0 * 8;
    const unsigned short* Bsrc1 = B + (bn + r1) * (size_t)K + c1 * 8;
    const int d0 = (tid & 448) * 8;
    const int d1 = (512 + (tid & 448)) * 8;

    const int arow = wr * 128 + lrow;
    const int brow = wc * 64 + lrow;
    const int kxu  = ((kseg * 16) ^ ((lrow >> 3) << 5)) >> 1;

    f32x4 acc[8][4] = {};
    bf16x8 aP[4], aQ[4], bP[4], bQ[4];
    const int NT = K >> 6;

    STAGE_A(0, 0, 0); STAGE_B(0, 0, 0); STAGE_A(0, 1, 0); STAGE_B(0, 1, 0);
    WAIT_VM(4);
    SBAR(); SCHED0();
    LDA4(aP, 0, 0, 0);
    LDB4(bP, 0, 0);
    SCHED0();

    for (int t = 0; t < NT; ++t) {
        const int bufc = t & 1, bufn = bufc ^ 1;
        const int k0n = (t + 1) << 6;
        const bool more = (t + 1 < NT);
        SBAR();
        WAIT_LGKM0(); SCHED0();
        if (more) STAGE_A(bufn, 0, k0n);
        __builtin_amdgcn_s_setprio(1);
        MFMAQ(0, aP, bP);
        __builtin_amdgcn_s_setprio(0);
        LDA4(aQ, 4, 0, bufc);
        SCHED0();
        WAIT_VM(2);
        SBAR();
        WAIT_LGKM0(); SCHED0();
        if (more) STAGE_B(bufn, 0, k0n);
        __builtin_amdgcn_s_setprio(1);
        MFMAQ(4, aQ, bP);
        __builtin_amdgcn_s_setprio(0);
        LDA4(aP, 0, 1, bufc);
        LDB4(bQ, 1, bufc);
        SCHED0();
        SBAR();
        WAIT_LGKM0(); SCHED0();
        if (more) STAGE_A(bufn, 1, k0n);
        __builtin_amdgcn_s_setprio(1);
        MFMAQ(0, aP, bQ);
        __builtin_amdgcn_s_setprio(0);
        LDA4(aQ, 4, 1, bufc);
        SCHED0();
        WAIT_VM(2);
        SBAR();
        WAIT_LGKM0(); SCHED0();
        if (more) STAGE_B(bufn, 1, k0n);
        __builtin_amdgcn_s_setprio(1);
        MFMAQ(4, aQ, bQ);
        __builtin_amdgcn_s_setprio(0);
        if (more) {
            LDA4(aP, 0, 0, bufn);
            LDB4(bP, 0, bufn);
        }
        SCHED0();
    }

    if (EPI == 0) {
        // ---- LDS-repack epilogue: 4 panels (256x64 bf16 = 32KB each),
        //      each panel CONTIGUOUS in global; 16 coalesced uint4/thread. ----
        const int p_ = (int)(bn >> 10);
        unsigned short* dstb = (p_ == 0) ? kb : (p_ == 1) ? vb :
                               (p_ == 2) ? rb : gb;
        const bool dosilu = (p_ == 3);
        const int b_ = (int)(bm >> 12);
        const int h0 = (int)((bn & 1023) >> 6);
        const int t0 = (int)(bm & 4095);

        SBAR();   // K-loop LDS reads complete on all waves
        {
            // wave owns panel wc (no LDS-pointer array: addrspacecast init fails)
            unsigned short* mybuf = (wc < 2) ? &As[wc][0] : &Bs[wc - 2][0];
            #pragma unroll
            for (int mi = 0; mi < 8; ++mi)
                #pragma unroll
                for (int ni = 0; ni < 4; ++ni)
                    #pragma unroll
                    for (int ri = 0; ri < 4; ++ri) {
                        const int row = wr * 128 + mi * 16 + kseg * 4 + ri;
                        const int col = ni * 16 + lrow;
                        float v = acc[mi][ni][ri];
                        if (dosilu) v = v / (1.f + __expf(-v));
                        *(unsigned short*)((char*)mybuf +
                            ((row * 128 + col * 2) ^ ((row & 7) << 4))) = f2bf(v);
                    }
        }
        SBAR();
        #pragma unroll
        for (int p = 0; p < 4; ++p) {
            const unsigned short* srcb = (p < 2) ? &As[p][0] : &Bs[p - 2][0];
            unsigned short* pb = dstb +
                (((size_t)(b_ * NH + h0 + p)) * TT + t0) * HD;
            #pragma unroll
            for (int it2 = 0; it2 < 4; ++it2) {
                const int o = it2 * 8192 + tid * 16;     // byte offset in panel
                const int row = o >> 7;
                uint4 val = *(const uint4*)((const char*)srcb +
                                            (o ^ ((row & 7) << 4)));
                *(uint4*)((char*)pb + o) = val;
            }
        }
    } else {
        #pragma unroll
        for (int mi = 0; mi < 8; ++mi) {
            const int mbase = (int)bm + wr * 128 + mi * 16 + kseg * 4;
            #pragma unroll
            for (int ni = 0; ni < 4; ++ni) {
                const int n = (int)bn + wc * 64 + ni * 16 + lrow;
                #pragma unroll
                for (int ri = 0; ri < 4; ++ri)
                    C[(size_t)(mbase + ri) * N + n] = acc[mi][ni][ri];
            }
        }
    }
}

// ============ MFMA chunk kernel: intra-chunk output + contrib ============
// Block = one (b,h,chunk). Exp factors hoisted out of the sb loop.

__global__ __launch_bounds__(256) void chunk_fused(
    const unsigned short* __restrict__ kb, const unsigned short* vb,
    const unsigned short* __restrict__ rb, const unsigned short* __restrict__ gb,
    const float* __restrict__ td, const float* __restrict__ tf,
    unsigned short* ctru, unsigned short* __restrict__ outp)
{
    __shared__ unsigned short KS [128 * 64];  // 16KB
    __shared__ unsigned short VT [64 * 128];  // 16KB (swz)
    __shared__ unsigned short Qm [32 * 64];   // 4KB (swz)
    __shared__ unsigned short QDm[32 * 64];   // 4KB (swz)
    __shared__ unsigned short KTB[32 * 64];   // 4KB (swz)
    __shared__ unsigned short KDT[64 * 32];   // 4KB (swz)
    __shared__ unsigned short PMt[32 * 32];   // 2KB (swz)
    __shared__ unsigned short SPT[64 * 64];   // 8KB (swz)

    const int bid  = blockIdx.x;
    const int c    = bid & (NC - 1);
    const int bh   = bid >> 5;
    const int h    = bh & (NH - 1);
    const int batch= bh >> 4;
    const int tid  = threadIdx.x;
    const int lane = tid & 63;
    const int w    = tid >> 6;
    const int lrow = lane & 15;
    const int kseg = lane >> 4;

    const float* tdh = td + h * HD;

    const unsigned short* kg_ = kb + ((size_t)bh * TT + (size_t)c * CL) * HD;
    const unsigned short* vg_ = vb + ((size_t)bh * TT + (size_t)c * CL) * HD;
    ((uint4*)KS)[tid]       = ((const uint4*)kg_)[tid];
    ((uint4*)KS)[tid + 256] = ((const uint4*)kg_)[tid + 256];
    ((uint4*)KS)[tid + 512] = ((const uint4*)kg_)[tid + 512];
    ((uint4*)KS)[tid + 768] = ((const uint4*)kg_)[tid + 768];
    #pragma unroll
    for (int it = 0; it < 4; ++it) {
        int ci = it * 256 + tid;
        uint4 r = ((const uint4*)vg_)[ci];
        int s = ci >> 3, j0 = (ci & 7) * 8;
        unsigned int vals[4] = { r.x, r.y, r.z, r.w };
        #pragma unroll
        for (int q = 0; q < 4; ++q) {
            int j1 = j0 + 2 * q, j2 = j1 + 1;
            *(unsigned short*)((char*)VT + ((j1 * 256 + s * 2) ^ ((j1 & 15) << 4)))
                = (unsigned short)(vals[q] & 0xffffu);
            *(unsigned short*)((char*)VT + ((j2 * 256 + s * 2) ^ ((j2 & 15) << 4)))
                = (unsigned short)(vals[q] >> 16);
        }
    }

    const int kkc = tid & 63;
    const float t1 = tdh[kkc];

    const float ed1 = __expf(-t1);          // d
    const float e31 = __expf(-31.f * t1);   // d^31
    float EQ[8], EQ1[8], EK[8], EKD[8];
    #pragma unroll
    for (int i8 = 0; i8 < 8; ++i8) {
        const float fr = (float)(i8 * 4 + w);
        EQ [i8] = __expf(-t1 * fr);         // d^r
        EK [i8] = __expf( t1 * fr);         // d^-r
        EQ1[i8] = EQ[i8] * ed1;             // d^(r+1)
        EKD[i8] = EK[i8] * e31;             // d^(31-r)
    }

    float e32[4];
    #pragma unroll
    for (int q = 0; q < 4; ++q)
        e32[q] = __expf(-32.f * tdh[16 * w + kseg * 4 + q]);

    const int it = w >> 1;
    const int st = w & 1;
    const int jt0 = (w & 1) * 2;

    f32x4 acc_S[4] = {};

    for (int sb = 0; sb < 4; ++sb) {
        const int s0 = sb * 32;
        __syncthreads();
        #pragma unroll
        for (int i8 = 0; i8 < 8; ++i8) {
            int r = i8 * 4 + w;
            float kf  = bfu(KS[(s0 + r) * 64 + kkc]);
            int rb2 = (r * 128 + kkc * 2) ^ ((r & 7) << 4);
            *(unsigned short*)((char*)Qm  + rb2) = f2bf(kf * EQ[i8]);
            *(unsigned short*)((char*)QDm + rb2) = f2bf(kf * EQ1[i8]);
            *(unsigned short*)((char*)KTB + rb2) = f2bf(kf * EK[i8]);
            *(unsigned short*)((char*)KDT + ((kkc * 64 + r * 2) ^ ((kkc & 3) << 4)))
                = f2bf(kf * EKD[i8]);
        }
        __syncthreads();
        {
            bf16x8 qa[2], kbf[2];
            #pragma unroll
            for (int ks = 0; ks < 2; ++ks) {
                qa[ks] = *(const bf16x8*)((const char*)Qm +
                    (it * 16 + lrow) * 128 + ((kseg * 16 + ks * 64) ^ ((lrow & 7) << 4)));
                kbf[ks] = *(const bf16x8*)((const char*)KTB +
                    (st * 16 + lrow) * 128 + ((kseg * 16 + ks * 64) ^ ((lrow & 7) << 4)));
            }
            f32x4 accP = {};
            accP = __builtin_amdgcn_mfma_f32_16x16x32_bf16(qa[0], kbf[0], accP, 0, 0, 0);
            accP = __builtin_amdgcn_mfma_f32_16x16x32_bf16(qa[1], kbf[1], accP, 0, 0, 0);
            #pragma unroll
            for (int q = 0; q < 4; ++q) {
                int i_ = it * 16 + kseg * 4 + q;
                int s_ = st * 16 + lrow;
                unsigned short pv = (s_ <= i_) ? f2bf(accP[q]) : (unsigned short)0;
                *(unsigned short*)((char*)PMt + ((i_ * 64 + s_ * 2) ^ ((i_ & 3) << 4))) = pv;
            }
        }
        {
            bf16x8 sa = *(const bf16x8*)((const char*)KDT +
                (16 * w + lrow) * 64 + ((kseg * 16) ^ ((lrow & 3) << 4)));
            #pragma unroll
            for (int jt = 0; jt < 4; ++jt) {
                #pragma unroll
                for (int q = 0; q < 4; ++q) acc_S[jt][q] *= e32[q];
                bf16x8 vbf = *(const bf16x8*)((const char*)VT +
                    (jt * 16 + lrow) * 256 + ((s0 * 2 + kseg * 16) ^ ((lrow & 15) << 4)));
                acc_S[jt] = __builtin_amdgcn_mfma_f32_16x16x32_bf16(sa, vbf, acc_S[jt], 0, 0, 0);
            }
        }
        __syncthreads();
        {
            bf16x8 pa = *(const bf16x8*)((const char*)PMt +
                (it * 16 + lrow) * 64 + ((kseg * 16) ^ ((lrow & 3) << 4)));
            bf16x8 qd[2];
            #pragma unroll
            for (int ks = 0; ks < 2; ++ks)
                qd[ks] = *(const bf16x8*)((const char*)QDm +
                    (it * 16 + lrow) * 128 + ((kseg * 16 + ks * 64) ^ ((lrow & 7) << 4)));
            #pragma unroll
            for (int jj = 0; jj < 2; ++jj) {
                const int jt = jt0 + jj;
                const int j_ = jt * 16 + lrow;
                bf16x8 vbf = *(const bf16x8*)((const char*)VT +
                    j_ * 256 + ((s0 * 2 + kseg * 16) ^ ((lrow & 15) << 4)));
                f32x4 accO = {};
                accO = __builtin_amdgcn_mfma_f32_16x16x32_bf16(pa, vbf, accO, 0, 0, 0);
                if (sb > 0) {
                    #pragma unroll
                    for (int ks = 0; ks < 2; ++ks) {
                        bf16x8 sp = *(const bf16x8*)((const char*)SPT +
                            j_ * 128 + ((kseg * 16 + ks * 64) ^ ((lrow & 7) << 4)));
                        accO = __builtin_amdgcn_mfma_f32_16x16x32_bf16(qd[ks], sp, accO, 0, 0, 0);
                    }
                }
                const float tfj = tf[h * HD + j_];
                #pragma unroll
                for (int q = 0; q < 4; ++q) {
                    int ip = it * 16 + kseg * 4 + q;
                    int t_ = c * CL + s0 + ip;
                    float kval = bfu(KS[(s0 + ip) * 64 + j_]);
                    float vval = bfu(*(const unsigned short*)((const char*)VT +
                        j_ * 256 + (((s0 + ip) * 2) ^ ((j_ & 15) << 4))));
                    float val = accO[q] + tfj * kval * vval;
                    size_t e = ((size_t)bh * TT + t_) * HD + j_;
                    float rgv = bfu(rb[e]) * bfu(gb[e]);
                    outp[((size_t)batch * TT + t_) * DIM + h * HD + j_] = f2bf(val * rgv);
                }
            }
        }
        __syncthreads();
        if (sb < 3) {
            #pragma unroll
            for (int jt = 0; jt < 4; ++jt) {
                const int j_ = jt * 16 + lrow;
                #pragma unroll
                for (int q = 0; q < 4; ++q) {
                    int kk_ = 16 * w + kseg * 4 + q;
                    *(unsigned short*)((char*)SPT +
                        ((j_ * 128 + kk_ * 2) ^ ((j_ & 7) << 4))) = f2bf(acc_S[jt][q]);
                }
            }
        }
    }

    unsigned short* cb = ctru + (size_t)bid * 8192;
    #pragma unroll
    for (int jt = 0; jt < 4; ++jt) {
        const int j_ = jt * 16 + lrow;
        uint2 pk;
        pk.x = (unsigned)f2bf(acc_S[jt][0]) | ((unsigned)f2bf(acc_S[jt][1]) << 16);
        pk.y = (unsigned)f2bf(acc_S[jt][2]) | ((unsigned)f2bf(acc_S[jt][3]) << 16);
        *(uint2*)&cb[j_ * 64 + 16 * w + kseg * 4] = pk;
    }
}

// ---------------- chunk-level scan: in-place ctr(bf16) -> s0t(bf16) ---------

__global__ __launch_bounds__(256) void chunk_scan(
    unsigned short* ctru, const float* __restrict__ td,
    float* __restrict__ state_out)
{
    int gtid = blockIdx.x * 256 + threadIdx.x;   // 0..262143
    int kk = gtid & 63;
    int j  = (gtid >> 6) & 63;
    int bh = gtid >> 12;
    int h  = bh & (NH - 1);
    float dC = __expf(-(float)CL * td[h * HD + kk]);  // d^CL
    float S = 0.f;
    unsigned short* cs = ctru + (size_t)bh * NC * 8192 + j * 64 + kk;
    for (int c = 0; c < NC; c++) {
        float t = bfu(cs[(size_t)c * 8192]);
        cs[(size_t)c * 8192] = f2bf(S);
        S = __builtin_fmaf(dC, S, t);
    }
    state_out[(size_t)bh * 4096 + kk * 64 + j] = S;
}

// ---------------- inter-chunk correction (MFMA) ----------------

__global__ __launch_bounds__(256) void chunk_corr(
    const unsigned short* __restrict__ kb, const unsigned short* __restrict__ rb,
    const unsigned short* __restrict__ gb,
    const float* __restrict__ td, const unsigned short* s0t,
    unsigned short* __restrict__ outp)
{
    const int bid = blockIdx.x;          // bh*NC + c
    const int c   = bid & (NC - 1);
    const int bh  = bid >> 5;
    const int h   = bh & (NH - 1);
    const int b   = bh >> 4;
    const int tid = threadIdx.x;
    const int lane = tid & 63;
    const int w    = tid >> 6;

    __shared__ unsigned short kd[CL * HD];   // 16KB, XOR-swizzled rows

    const int srow = tid >> 3;
    const int kk0  = (tid & 7) * 8;
    float tdv[8];
    #pragma unroll
    for (int e = 0; e < 8; e++) tdv[e] = td[h * HD + kk0 + e];
    const unsigned short* kbase = kb + ((size_t)bh * TT + (size_t)c * CL) * HD;
    #pragma unroll
    for (int it = 0; it < 4; it++) {
        const int row = it * 32 + srow;
        uint4 r = *(const uint4*)(kbase + (size_t)row * HD + kk0);
        const float fi = -(float)(row + 1);
        unsigned int rr[4] = { r.x, r.y, r.z, r.w };
        unsigned int o[4];
        #pragma unroll
        for (int q = 0; q < 4; q++) {
            float lo = bfu(rr[q])       * __expf(fi * tdv[2*q]);
            float hi = bfu(rr[q] >> 16) * __expf(fi * tdv[2*q+1]);
            o[q] = (unsigned)f2bf(lo) | ((unsigned)f2bf(hi) << 16);
        }
        *(uint4*)((char*)kd + row * 128 + ((kk0 * 2) ^ ((row & 7) << 4))) =
            make_uint4(o[0], o[1], o[2], o[3]);
    }
    __syncthreads();

    const int lrow = lane & 15;
    const int g    = lane >> 4;

    bf16x8 afr[2][4], bfr[2][2];
    const unsigned short* sbase = s0t + (size_t)bid * 8192;
    #pragma unroll
    for (int ks = 0; ks < 2; ks++)
        #pragma unroll
        for (int vt = 0; vt < 4; vt++)
            afr[ks][vt] = *(const bf16x8*)(sbase + (vt * 16 + lrow) * 64 + g * 8 + ks * 32);
    #pragma unroll
    for (int ks = 0; ks < 2; ks++)
        #pragma unroll
        for (int bt = 0; bt < 2; bt++) {
            const int row = w * 32 + bt * 16 + lrow;
            bfr[ks][bt] = *(const bf16x8*)((const char*)kd + row * 128 +
                (((g * 8 + ks * 32) * 2) ^ ((row & 7) << 4)));
        }

    f32x4 acc[4][2] = {};
    #pragma unroll
    for (int ks = 0; ks < 2; ks++)
        #pragma unroll
        for (int vt = 0; vt < 4; vt++)
            #pragma unroll
            for (int bt = 0; bt < 2; bt++)
                acc[vt][bt] = __builtin_amdgcn_mfma_f32_16x16x32_bf16(
                    afr[ks][vt], bfr[ks][bt], acc[vt][bt], 0, 0, 0);

    #pragma unroll
    for (int bt = 0; bt < 2; bt++) {
        const int i = w * 32 + bt * 16 + lrow;
        const size_t t = (size_t)c * CL + i;
        const unsigned short* rrow2 = rb + ((size_t)bh * TT + t) * HD;
        const unsigned short* grow2 = gb + ((size_t)bh * TT + t) * HD;
        unsigned short* orow = outp + ((size_t)b * TT + t) * DIM + h * HD;
        #pragma unroll
        for (int vt = 0; vt < 4; vt++)
            #pragma unroll
            for (int ri = 0; ri < 4; ri++) {
                const int v = vt * 16 + 4 * g + ri;
                float val = bfu(orow[v]) +
                            bfu(rrow2[v]) * bfu(grow2[v]) * acc[vt][bt][ri];
                orow[v] = f2bf(val);
            }
    }
}

// ---------------- launch ----------------
// Workspace map (bytes), peak 170 MB:
//   [0,32M)      xx (bf16)       -> reused as outp (bf16) after gemm1
//   [32M,40M)    wcat (bf16)
//   [40M,42M)    wob (bf16)
//   [42M,74M)    kb
//   [74M,106M)   vb  -> per-chunk dead regions reused as bf16 ctr (stride 8192)
//                       then in-place s0t after chunk_scan
//   [106M,138M)  rb
//   [138M,170M)  gb

static const size_t OFF_XX   = 0;
static const size_t OFF_WCAT = 33554432;
static const size_t OFF_WO   = 41943040;
static const size_t OFF_K    = 44040192;
static const size_t OFF_V    = 77594624;
static const size_t OFF_R    = 111149056;
static const size_t OFF_G    = 144703488;
static const size_t OFF_OP   = 0;           // aliases xx

extern "C" void kernel_launch(void* const* d_in, const int* in_sizes, int n_in,
                              void* d_out, int out_size, void* d_ws, size_t ws_size,
                              hipStream_t stream) {
    const float* x   = (const float*)d_in[0];
    const float* tmx = (const float*)d_in[1];
    const float* td  = (const float*)d_in[2];
    const float* tf  = (const float*)d_in[3];
    const float* Wk  = (const float*)d_in[4];
    const float* Wv  = (const float*)d_in[5];
    const float* Wr  = (const float*)d_in[6];
    const float* Wg  = (const float*)d_in[7];
    const float* Wo  = (const float*)d_in[8];

    char* ws = (char*)d_ws;
    unsigned short* xx   = (unsigned short*)(ws + OFF_XX);
    unsigned short* wcat = (unsigned short*)(ws + OFF_WCAT);
    unsigned short* wob  = (unsigned short*)(ws + OFF_WO);
    unsigned short* kb   = (unsigned short*)(ws + OFF_K);
    unsigned short* vb   = (unsigned short*)(ws + OFF_V);
    unsigned short* rb   = (unsigned short*)(ws + OFF_R);
    unsigned short* gb   = (unsigned short*)(ws + OFF_G);
    unsigned short* ctru = (unsigned short*)(ws + OFF_V);   // aliases vb
    unsigned short* outp = (unsigned short*)(ws + OFF_OP);

    float* out       = (float*)d_out;
    float* state_out = out + (size_t)BT * DIM;

    conv_x_kernel<<<16384, 256, 0, stream>>>(x, tmx, xx);
    conv_w_kernel<<<5120, 256, 0, stream>>>(Wk, Wv, Wr, Wg, Wo, wcat, wob);
    gemm256<0><<<1024, 512, 0, stream>>>(xx, wcat, nullptr,
                                         BT, 4096, 1024, kb, vb, rb, gb);
    chunk_fused<<<64 * NC, 256, 0, stream>>>(kb, vb, rb, gb, td, tf, ctru, outp);
    chunk_scan<<<1024, 256, 0, stream>>>(ctru, td, state_out);
    chunk_corr<<<64 * NC, 256, 0, stream>>>(kb, rb, gb, td, ctru, outp);
    gemm256<1><<<256, 512, 0, stream>>>(outp, wob, out,
                                        BT, 1024, 1024,
                                        nullptr, nullptr, nullptr, nullptr);
}

// Round 15
// 311.811 us; speedup vs baseline: 1.0479x; 1.0479x over previous
//
#include <hip/hip_runtime.h>
#include <stdint.h>

#define DIM 1024
#define NH  16
#define HD  64
#define BB  4
#define TT  4096
#define BT  (BB*TT)   // 16384
#define NC  32        // number of chunks
#define CL  128       // chunk length

typedef __bf16 bf16x8 __attribute__((ext_vector_type(8)));
typedef float  f32x4  __attribute__((ext_vector_type(4)));

__device__ __forceinline__ float bfu(unsigned int u) {
    return __uint_as_float((u & 0xffffu) << 16);
}
__device__ __forceinline__ unsigned short f2bf(float f) {
    unsigned int u = __float_as_uint(f);
    u += 0x7fffu + ((u >> 16) & 1u);
    return (unsigned short)(u >> 16);
}

__device__ __forceinline__ void gload16(const void* g, void* lds) {
    __builtin_amdgcn_global_load_lds((__attribute__((address_space(1))) void*)g,
                                     (__attribute__((address_space(3))) void*)lds,
                                     16, 0, 0);
}

// ---------------- elementwise converters ----------------

__global__ __launch_bounds__(256) void conv_x_kernel(
    const float* __restrict__ x, const float* __restrict__ tmix,
    unsigned short* __restrict__ xx)
{
    int gid = blockIdx.x * 256 + threadIdx.x;          // 4 elems per thread
    float4 xv = ((const float4*)x)[gid];
    float4 tv = ((const float4*)tmix)[gid & 255];
    uint2 o;
    o.x = (unsigned)f2bf(xv.x * tv.x) | ((unsigned)f2bf(xv.y * tv.y) << 16);
    o.y = (unsigned)f2bf(xv.z * tv.z) | ((unsigned)f2bf(xv.w * tv.w) << 16);
    ((uint2*)xx)[gid] = o;
}

__global__ __launch_bounds__(256) void conv_w_kernel(
    const float* __restrict__ Wk, const float* __restrict__ Wv,
    const float* __restrict__ Wr, const float* __restrict__ Wg,
    const float* __restrict__ Wo,
    unsigned short* __restrict__ wcat, unsigned short* __restrict__ wob)
{
    int gid = blockIdx.x * 256 + threadIdx.x;          // 0..1310719
    size_t idx = (size_t)gid * 4;
    float4 v;
    unsigned short* dst;
    if (idx < 4194304) {
        int p = (int)(idx >> 20);
        size_t loc = idx & 1048575;
        const float* src = (p == 0) ? Wk : (p == 1) ? Wv : (p == 2) ? Wr : Wg;
        v = ((const float4*)src)[loc >> 2];
        dst = wcat + idx;
    } else {
        size_t loc = idx - 4194304;
        v = ((const float4*)Wo)[loc >> 2];
        dst = wob + loc;
    }
    uint2 o;
    o.x = (unsigned)f2bf(v.x) | ((unsigned)f2bf(v.y) << 16);
    o.y = (unsigned)f2bf(v.z) | ((unsigned)f2bf(v.w) << 16);
    *(uint2*)dst = o;
}

// ============ 256x256 8-phase bf16 MFMA GEMM (A[M,K] * B[N,K]^T) ============
// (R7/R9-proven schedule; R12 2D-XCD map; scatter epilogue — best measured.)

#define MFMAQ(accb, av, bv)                                                    \
    _Pragma("unroll") for (int mi_ = 0; mi_ < 4; ++mi_)                        \
    _Pragma("unroll") for (int ni_ = 0; ni_ < 4; ++ni_)                        \
        acc[(accb)+mi_][ni_] = __builtin_amdgcn_mfma_f32_16x16x32_bf16(        \
            av[mi_], bv[ni_], acc[(accb)+mi_][ni_], 0, 0, 0);

#define LDA4(dst, mib, kh, bi)                                                 \
    _Pragma("unroll") for (int q_ = 0; q_ < 4; ++q_)                           \
        dst[q_] = *(const bf16x8*)&As[bi][(kh)*8192 + (arow + ((mib)+q_)*16)*32 + kxu];

#define LDB4(dst, kh, bi)                                                      \
    _Pragma("unroll") for (int q_ = 0; q_ < 4; ++q_)                           \
        dst[q_] = *(const bf16x8*)&Bs[bi][(kh)*8192 + (brow + q_*16)*32 + kxu];

#define STAGE_A(nb, kh, k0e) do {                                              \
    gload16(Asrc0 + (k0e) + (kh)*32, &As[nb][(kh)*8192 + d0]);                 \
    gload16(Asrc1 + (k0e) + (kh)*32, &As[nb][(kh)*8192 + d1]); } while (0)

#define STAGE_B(nb, kh, k0e) do {                                              \
    gload16(Bsrc0 + (k0e) + (kh)*32, &Bs[nb][(kh)*8192 + d0]);                 \
    gload16(Bsrc1 + (k0e) + (kh)*32, &Bs[nb][(kh)*8192 + d1]); } while (0)

#define SBAR()  __builtin_amdgcn_s_barrier()
#define SCHED0() __builtin_amdgcn_sched_barrier(0)
#define WAIT_LGKM0() asm volatile("s_waitcnt lgkmcnt(0)" ::: "memory")
#define WAIT_VM(n)   asm volatile("s_waitcnt vmcnt(" #n ")" ::: "memory")

template<int EPI>
__global__ __launch_bounds__(512, 2) void gemm256(
    const unsigned short* __restrict__ A, const unsigned short* __restrict__ B,
    float* __restrict__ C, int M, int N, int K,
    unsigned short* __restrict__ kb, unsigned short* __restrict__ vb,
    unsigned short* __restrict__ rb, unsigned short* __restrict__ gb)
{
    __shared__ unsigned short As[2][16384];   // 64 KB
    __shared__ unsigned short Bs[2][16384];   // 64 KB

    const int tid  = threadIdx.x;
    const int lane = tid & 63;
    const int wv   = tid >> 6;
    const int wr   = wv >> 2;      // 0..1  (M)
    const int wc   = wv & 3;       // 0..3  (N)
    const int lrow = lane & 15;
    const int kseg = lane >> 4;    // 0..3

    const int bid = blockIdx.x;
    int bx, by;
    if (EPI == 0) {
        // gemm1: 1024 blocks = 64M x 16N. XCD x owns M-rows [8x,8x+8), all N,
        // traversed in 4x4 sub-tiles (R12: FETCH 147->98 MB, at analytic floor).
        const int xcd = bid & 7, q = bid >> 3;         // q in [0,128)
        const int dm = (q >> 2) & 3, dn = q & 3;
        const int sn = (q >> 4) & 3, sm = q >> 6;      // sm in [0,2)
        by = xcd * 8 + sm * 4 + dm;
        bx = sn * 4 + dn;
    } else {
        const int nwg = gridDim.x;
        const int cpx = nwg >> 3;
        const int wg  = (bid & 7) * cpx + (bid >> 3);
        const int nbx = N >> 8;
        bx = wg % nbx; by = wg / nbx;
    }
    const size_t bm = (size_t)by * 256, bn = (size_t)bx * 256;

    const int r0 = tid >> 2;
    const int c0 = (tid & 3) ^ (((tid >> 5) & 1) << 1);
    const int r1 = (512 + tid) >> 2;
    const int c1 = (tid & 3) ^ ((((512 + tid) >> 5) & 1) << 1);
    const unsigned short* Asrc0 = A + (bm + r0) * (size_t)K + c0 * 8;
    const unsigned short* Asrc1 = A + (bm + r1) * (size_t)K + c1 * 8;
    const unsigned short* Bsrc0 = B + (bn + r0) * (size_t)K + c0 * 8;
    const unsigned short* Bsrc1 = B + (bn + r1) * (size_t)K + c1 * 8;
    const int d0 = (tid & 448) * 8;
    const int d1 = (512 + (tid & 448)) * 8;

    const int arow = wr * 128 + lrow;
    const int brow = wc * 64 + lrow;
    const int kxu  = ((kseg * 16) ^ ((lrow >> 3) << 5)) >> 1;

    f32x4 acc[8][4] = {};
    bf16x8 aP[4], aQ[4], bP[4], bQ[4];
    const int NT = K >> 6;

    STAGE_A(0, 0, 0); STAGE_B(0, 0, 0); STAGE_A(0, 1, 0); STAGE_B(0, 1, 0);
    WAIT_VM(4);
    SBAR(); SCHED0();
    LDA4(aP, 0, 0, 0);
    LDB4(bP, 0, 0);
    SCHED0();

    for (int t = 0; t < NT; ++t) {
        const int bufc = t & 1, bufn = bufc ^ 1;
        const int k0n = (t + 1) << 6;
        const bool more = (t + 1 < NT);
        SBAR();
        WAIT_LGKM0(); SCHED0();
        if (more) STAGE_A(bufn, 0, k0n);
        __builtin_amdgcn_s_setprio(1);
        MFMAQ(0, aP, bP);
        __builtin_amdgcn_s_setprio(0);
        LDA4(aQ, 4, 0, bufc);
        SCHED0();
        WAIT_VM(2);
        SBAR();
        WAIT_LGKM0(); SCHED0();
        if (more) STAGE_B(bufn, 0, k0n);
        __builtin_amdgcn_s_setprio(1);
        MFMAQ(4, aQ, bP);
        __builtin_amdgcn_s_setprio(0);
        LDA4(aP, 0, 1, bufc);
        LDB4(bQ, 1, bufc);
        SCHED0();
        SBAR();
        WAIT_LGKM0(); SCHED0();
        if (more) STAGE_A(bufn, 1, k0n);
        __builtin_amdgcn_s_setprio(1);
        MFMAQ(0, aP, bQ);
        __builtin_amdgcn_s_setprio(0);
        LDA4(aQ, 4, 1, bufc);
        SCHED0();
        WAIT_VM(2);
        SBAR();
        WAIT_LGKM0(); SCHED0();
        if (more) STAGE_B(bufn, 1, k0n);
        __builtin_amdgcn_s_setprio(1);
        MFMAQ(4, aQ, bQ);
        __builtin_amdgcn_s_setprio(0);
        if (more) {
            LDA4(aP, 0, 0, bufn);
            LDB4(bP, 0, bufn);
        }
        SCHED0();
    }

    if (EPI == 0) {
        const int p = (int)(bn >> 10);
        unsigned short* dst = (p == 0) ? kb : (p == 1) ? vb : (p == 2) ? rb : gb;
        #pragma unroll
        for (int mi = 0; mi < 8; ++mi) {
            const int mbase = (int)bm + wr * 128 + mi * 16 + kseg * 4;
            #pragma unroll
            for (int ni = 0; ni < 4; ++ni) {
                const int n = (int)bn + wc * 64 + ni * 16 + lrow;
                const int e = n & 1023;
                const int h = e >> 6, j = e & 63;
                #pragma unroll
                for (int ri = 0; ri < 4; ++ri) {
                    const int m = mbase + ri;
                    const int b = m >> 12, tt = m & 4095;
                    float v = acc[mi][ni][ri];
                    if (p == 3) v = v / (1.f + __expf(-v));  // silu
                    dst[(((size_t)(b * NH + h)) * TT + tt) * HD + j] = f2bf(v);
                }
            }
        }
    } else {
        #pragma unroll
        for (int mi = 0; mi < 8; ++mi) {
            const int mbase = (int)bm + wr * 128 + mi * 16 + kseg * 4;
            #pragma unroll
            for (int ni = 0; ni < 4; ++ni) {
                const int n = (int)bn + wc * 64 + ni * 16 + lrow;
                #pragma unroll
                for (int ri = 0; ri < 4; ++ri)
                    C[(size_t)(mbase + ri) * N + n] = acc[mi][ni][ri];
            }
        }
    }
}

// ============ MFMA chunk kernel: intra-chunk output + contrib ============
// Block = one (b,h,chunk). Exp factors hoisted out of the sb loop.

__global__ __launch_bounds__(256) void chunk_fused(
    const unsigned short* __restrict__ kb, const unsigned short* vb,
    const unsigned short* __restrict__ rb, const unsigned short* __restrict__ gb,
    const float* __restrict__ td, const float* __restrict__ tf,
    unsigned short* ctru, unsigned short* __restrict__ outp)
{
    __shared__ unsigned short KS [128 * 64];  // 16KB
    __shared__ unsigned short VT [64 * 128];  // 16KB (swz)
    __shared__ unsigned short Qm [32 * 64];   // 4KB (swz)
    __shared__ unsigned short QDm[32 * 64];   // 4KB (swz)
    __shared__ unsigned short KTB[32 * 64];   // 4KB (swz)
    __shared__ unsigned short KDT[64 * 32];   // 4KB (swz)
    __shared__ unsigned short PMt[32 * 32];   // 2KB (swz)
    __shared__ unsigned short SPT[64 * 64];   // 8KB (swz)

    const int bid  = blockIdx.x;
    const int c    = bid & (NC - 1);
    const int bh   = bid >> 5;
    const int h    = bh & (NH - 1);
    const int batch= bh >> 4;
    const int tid  = threadIdx.x;
    const int lane = tid & 63;
    const int w    = tid >> 6;
    const int lrow = lane & 15;
    const int kseg = lane >> 4;

    const float* tdh = td + h * HD;

    const unsigned short* kg_ = kb + ((size_t)bh * TT + (size_t)c * CL) * HD;
    const unsigned short* vg_ = vb + ((size_t)bh * TT + (size_t)c * CL) * HD;
    ((uint4*)KS)[tid]       = ((const uint4*)kg_)[tid];
    ((uint4*)KS)[tid + 256] = ((const uint4*)kg_)[tid + 256];
    ((uint4*)KS)[tid + 512] = ((const uint4*)kg_)[tid + 512];
    ((uint4*)KS)[tid + 768] = ((const uint4*)kg_)[tid + 768];
    #pragma unroll
    for (int it = 0; it < 4; ++it) {
        int ci = it * 256 + tid;
        uint4 r = ((const uint4*)vg_)[ci];
        int s = ci >> 3, j0 = (ci & 7) * 8;
        unsigned int vals[4] = { r.x, r.y, r.z, r.w };
        #pragma unroll
        for (int q = 0; q < 4; ++q) {
            int j1 = j0 + 2 * q, j2 = j1 + 1;
            *(unsigned short*)((char*)VT + ((j1 * 256 + s * 2) ^ ((j1 & 15) << 4)))
                = (unsigned short)(vals[q] & 0xffffu);
            *(unsigned short*)((char*)VT + ((j2 * 256 + s * 2) ^ ((j2 & 15) << 4)))
                = (unsigned short)(vals[q] >> 16);
        }
    }

    const int kkc = tid & 63;
    const float t1 = tdh[kkc];

    const float ed1 = __expf(-t1);          // d
    const float e31 = __expf(-31.f * t1);   // d^31
    float EQ[8], EQ1[8], EK[8], EKD[8];
    #pragma unroll
    for (int i8 = 0; i8 < 8; ++i8) {
        const float fr = (float)(i8 * 4 + w);
        EQ [i8] = __expf(-t1 * fr);         // d^r
        EK [i8] = __expf( t1 * fr);         // d^-r
        EQ1[i8] = EQ[i8] * ed1;             // d^(r+1)
        EKD[i8] = EK[i8] * e31;             // d^(31-r)
    }

    float e32[4];
    #pragma unroll
    for (int q = 0; q < 4; ++q)
        e32[q] = __expf(-32.f * tdh[16 * w + kseg * 4 + q]);

    const int it = w >> 1;
    const int st = w & 1;
    const int jt0 = (w & 1) * 2;

    f32x4 acc_S[4] = {};

    for (int sb = 0; sb < 4; ++sb) {
        const int s0 = sb * 32;
        __syncthreads();
        #pragma unroll
        for (int i8 = 0; i8 < 8; ++i8) {
            int r = i8 * 4 + w;
            float kf  = bfu(KS[(s0 + r) * 64 + kkc]);
            int rb2 = (r * 128 + kkc * 2) ^ ((r & 7) << 4);
            *(unsigned short*)((char*)Qm  + rb2) = f2bf(kf * EQ[i8]);
            *(unsigned short*)((char*)QDm + rb2) = f2bf(kf * EQ1[i8]);
            *(unsigned short*)((char*)KTB + rb2) = f2bf(kf * EK[i8]);
            *(unsigned short*)((char*)KDT + ((kkc * 64 + r * 2) ^ ((kkc & 3) << 4)))
                = f2bf(kf * EKD[i8]);
        }
        __syncthreads();
        {
            bf16x8 qa[2], kbf[2];
            #pragma unroll
            for (int ks = 0; ks < 2; ++ks) {
                qa[ks] = *(const bf16x8*)((const char*)Qm +
                    (it * 16 + lrow) * 128 + ((kseg * 16 + ks * 64) ^ ((lrow & 7) << 4)));
                kbf[ks] = *(const bf16x8*)((const char*)KTB +
                    (st * 16 + lrow) * 128 + ((kseg * 16 + ks * 64) ^ ((lrow & 7) << 4)));
            }
            f32x4 accP = {};
            accP = __builtin_amdgcn_mfma_f32_16x16x32_bf16(qa[0], kbf[0], accP, 0, 0, 0);
            accP = __builtin_amdgcn_mfma_f32_16x16x32_bf16(qa[1], kbf[1], accP, 0, 0, 0);
            #pragma unroll
            for (int q = 0; q < 4; ++q) {
                int i_ = it * 16 + kseg * 4 + q;
                int s_ = st * 16 + lrow;
                unsigned short pv = (s_ <= i_) ? f2bf(accP[q]) : (unsigned short)0;
                *(unsigned short*)((char*)PMt + ((i_ * 64 + s_ * 2) ^ ((i_ & 3) << 4))) = pv;
            }
        }
        {
            bf16x8 sa = *(const bf16x8*)((const char*)KDT +
                (16 * w + lrow) * 64 + ((kseg * 16) ^ ((lrow & 3) << 4)));
            #pragma unroll
            for (int jt = 0; jt < 4; ++jt) {
                #pragma unroll
                for (int q = 0; q < 4; ++q) acc_S[jt][q] *= e32[q];
                bf16x8 vbf = *(const bf16x8*)((const char*)VT +
                    (jt * 16 + lrow) * 256 + ((s0 * 2 + kseg * 16) ^ ((lrow & 15) << 4)));
                acc_S[jt] = __builtin_amdgcn_mfma_f32_16x16x32_bf16(sa, vbf, acc_S[jt], 0, 0, 0);
            }
        }
        __syncthreads();
        {
            bf16x8 pa = *(const bf16x8*)((const char*)PMt +
                (it * 16 + lrow) * 64 + ((kseg * 16) ^ ((lrow & 3) << 4)));
            bf16x8 qd[2];
            #pragma unroll
            for (int ks = 0; ks < 2; ++ks)
                qd[ks] = *(const bf16x8*)((const char*)QDm +
                    (it * 16 + lrow) * 128 + ((kseg * 16 + ks * 64) ^ ((lrow & 7) << 4)));
            #pragma unroll
            for (int jj = 0; jj < 2; ++jj) {
                const int jt = jt0 + jj;
                const int j_ = jt * 16 + lrow;
                bf16x8 vbf = *(const bf16x8*)((const char*)VT +
                    j_ * 256 + ((s0 * 2 + kseg * 16) ^ ((lrow & 15) << 4)));
                f32x4 accO = {};
                accO = __builtin_amdgcn_mfma_f32_16x16x32_bf16(pa, vbf, accO, 0, 0, 0);
                if (sb > 0) {
                    #pragma unroll
                    for (int ks = 0; ks < 2; ++ks) {
                        bf16x8 sp = *(const bf16x8*)((const char*)SPT +
                            j_ * 128 + ((kseg * 16 + ks * 64) ^ ((lrow & 7) << 4)));
                        accO = __builtin_amdgcn_mfma_f32_16x16x32_bf16(qd[ks], sp, accO, 0, 0, 0);
                    }
                }
                const float tfj = tf[h * HD + j_];
                #pragma unroll
                for (int q = 0; q < 4; ++q) {
                    int ip = it * 16 + kseg * 4 + q;
                    int t_ = c * CL + s0 + ip;
                    float kval = bfu(KS[(s0 + ip) * 64 + j_]);
                    float vval = bfu(*(const unsigned short*)((const char*)VT +
                        j_ * 256 + (((s0 + ip) * 2) ^ ((j_ & 15) << 4))));
                    float val = accO[q] + tfj * kval * vval;
                    size_t e = ((size_t)bh * TT + t_) * HD + j_;
                    float rgv = bfu(rb[e]) * bfu(gb[e]);
                    outp[((size_t)batch * TT + t_) * DIM + h * HD + j_] = f2bf(val * rgv);
                }
            }
        }
        __syncthreads();
        if (sb < 3) {
            #pragma unroll
            for (int jt = 0; jt < 4; ++jt) {
                const int j_ = jt * 16 + lrow;
                #pragma unroll
                for (int q = 0; q < 4; ++q) {
                    int kk_ = 16 * w + kseg * 4 + q;
                    *(unsigned short*)((char*)SPT +
                        ((j_ * 128 + kk_ * 2) ^ ((j_ & 7) << 4))) = f2bf(acc_S[jt][q]);
                }
            }
        }
    }

    unsigned short* cb = ctru + (size_t)bid * 8192;
    #pragma unroll
    for (int jt = 0; jt < 4; ++jt) {
        const int j_ = jt * 16 + lrow;
        uint2 pk;
        pk.x = (unsigned)f2bf(acc_S[jt][0]) | ((unsigned)f2bf(acc_S[jt][1]) << 16);
        pk.y = (unsigned)f2bf(acc_S[jt][2]) | ((unsigned)f2bf(acc_S[jt][3]) << 16);
        *(uint2*)&cb[j_ * 64 + 16 * w + kseg * 4] = pk;
    }
}

// ---------------- chunk-level scan: in-place ctr(bf16) -> s0t(bf16) ---------

__global__ __launch_bounds__(256) void chunk_scan(
    unsigned short* ctru, const float* __restrict__ td,
    float* __restrict__ state_out)
{
    int gtid = blockIdx.x * 256 + threadIdx.x;   // 0..262143
    int kk = gtid & 63;
    int j  = (gtid >> 6) & 63;
    int bh = gtid >> 12;
    int h  = bh & (NH - 1);
    float dC = __expf(-(float)CL * td[h * HD + kk]);  // d^CL
    float S = 0.f;
    unsigned short* cs = ctru + (size_t)bh * NC * 8192 + j * 64 + kk;
    for (int c = 0; c < NC; c++) {
        float t = bfu(cs[(size_t)c * 8192]);
        cs[(size_t)c * 8192] = f2bf(S);
        S = __builtin_fmaf(dC, S, t);
    }
    state_out[(size_t)bh * 4096 + kk * 64 + j] = S;
}

// ---------------- inter-chunk correction (MFMA) ----------------

__global__ __launch_bounds__(256) void chunk_corr(
    const unsigned short* __restrict__ kb, const unsigned short* __restrict__ rb,
    const unsigned short* __restrict__ gb,
    const float* __restrict__ td, const unsigned short* s0t,
    unsigned short* __restrict__ outp)
{
    const int bid = blockIdx.x;          // bh*NC + c
    const int c   = bid & (NC - 1);
    const int bh  = bid >> 5;
    const int h   = bh & (NH - 1);
    const int b   = bh >> 4;
    const int tid = threadIdx.x;
    const int lane = tid & 63;
    const int w    = tid >> 6;

    __shared__ unsigned short kd[CL * HD];   // 16KB, XOR-swizzled rows

    const int srow = tid >> 3;
    const int kk0  = (tid & 7) * 8;
    float tdv[8];
    #pragma unroll
    for (int e = 0; e < 8; e++) tdv[e] = td[h * HD + kk0 + e];
    const unsigned short* kbase = kb + ((size_t)bh * TT + (size_t)c * CL) * HD;
    #pragma unroll
    for (int it = 0; it < 4; it++) {
        const int row = it * 32 + srow;
        uint4 r = *(const uint4*)(kbase + (size_t)row * HD + kk0);
        const float fi = -(float)(row + 1);
        unsigned int rr[4] = { r.x, r.y, r.z, r.w };
        unsigned int o[4];
        #pragma unroll
        for (int q = 0; q < 4; q++) {
            float lo = bfu(rr[q])       * __expf(fi * tdv[2*q]);
            float hi = bfu(rr[q] >> 16) * __expf(fi * tdv[2*q+1]);
            o[q] = (unsigned)f2bf(lo) | ((unsigned)f2bf(hi) << 16);
        }
        *(uint4*)((char*)kd + row * 128 + ((kk0 * 2) ^ ((row & 7) << 4))) =
            make_uint4(o[0], o[1], o[2], o[3]);
    }
    __syncthreads();

    const int lrow = lane & 15;
    const int g    = lane >> 4;

    bf16x8 afr[2][4], bfr[2][2];
    const unsigned short* sbase = s0t + (size_t)bid * 8192;
    #pragma unroll
    for (int ks = 0; ks < 2; ks++)
        #pragma unroll
        for (int vt = 0; vt < 4; vt++)
            afr[ks][vt] = *(const bf16x8*)(sbase + (vt * 16 + lrow) * 64 + g * 8 + ks * 32);
    #pragma unroll
    for (int ks = 0; ks < 2; ks++)
        #pragma unroll
        for (int bt = 0; bt < 2; bt++) {
            const int row = w * 32 + bt * 16 + lrow;
            bfr[ks][bt] = *(const bf16x8*)((const char*)kd + row * 128 +
                (((g * 8 + ks * 32) * 2) ^ ((row & 7) << 4)));
        }

    f32x4 acc[4][2] = {};
    #pragma unroll
    for (int ks = 0; ks < 2; ks++)
        #pragma unroll
        for (int vt = 0; vt < 4; vt++)
            #pragma unroll
            for (int bt = 0; bt < 2; bt++)
                acc[vt][bt] = __builtin_amdgcn_mfma_f32_16x16x32_bf16(
                    afr[ks][vt], bfr[ks][bt], acc[vt][bt], 0, 0, 0);

    #pragma unroll
    for (int bt = 0; bt < 2; bt++) {
        const int i = w * 32 + bt * 16 + lrow;
        const size_t t = (size_t)c * CL + i;
        const unsigned short* rrow2 = rb + ((size_t)bh * TT + t) * HD;
        const unsigned short* grow2 = gb + ((size_t)bh * TT + t) * HD;
        unsigned short* orow = outp + ((size_t)b * TT + t) * DIM + h * HD;
        #pragma unroll
        for (int vt = 0; vt < 4; vt++)
            #pragma unroll
            for (int ri = 0; ri < 4; ri++) {
                const int v = vt * 16 + 4 * g + ri;
                float val = bfu(orow[v]) +
                            bfu(rrow2[v]) * bfu(grow2[v]) * acc[vt][bt][ri];
                orow[v] = f2bf(val);
            }
    }
}

// ---------------- launch ----------------
// Workspace map (bytes), peak 170 MB:
//   [0,32M)      xx (bf16)       -> reused as outp (bf16) after gemm1
//   [32M,40M)    wcat (bf16)
//   [40M,42M)    wob (bf16)
//   [42M,74M)    kb
//   [74M,106M)   vb  -> per-chunk dead regions reused as bf16 ctr (stride 8192)
//                       then in-place s0t after chunk_scan
//   [106M,138M)  rb
//   [138M,170M)  gb

static const size_t OFF_XX   = 0;
static const size_t OFF_WCAT = 33554432;
static const size_t OFF_WO   = 41943040;
static const size_t OFF_K    = 44040192;
static const size_t OFF_V    = 77594624;
static const size_t OFF_R    = 111149056;
static const size_t OFF_G    = 144703488;
static const size_t OFF_OP   = 0;           // aliases xx

extern "C" void kernel_launch(void* const* d_in, const int* in_sizes, int n_in,
                              void* d_out, int out_size, void* d_ws, size_t ws_size,
                              hipStream_t stream) {
    const float* x   = (const float*)d_in[0];
    const float* tmx = (const float*)d_in[1];
    const float* td  = (const float*)d_in[2];
    const float* tf  = (const float*)d_in[3];
    const float* Wk  = (const float*)d_in[4];
    const float* Wv  = (const float*)d_in[5];
    const float* Wr  = (const float*)d_in[6];
    const float* Wg  = (const float*)d_in[7];
    const float* Wo  = (const float*)d_in[8];

    char* ws = (char*)d_ws;
    unsigned short* xx   = (unsigned short*)(ws + OFF_XX);
    unsigned short* wcat = (unsigned short*)(ws + OFF_WCAT);
    unsigned short* wob  = (unsigned short*)(ws + OFF_WO);
    unsigned short* kb   = (unsigned short*)(ws + OFF_K);
    unsigned short* vb   = (unsigned short*)(ws + OFF_V);
    unsigned short* rb   = (unsigned short*)(ws + OFF_R);
    unsigned short* gb   = (unsigned short*)(ws + OFF_G);
    unsigned short* ctru = (unsigned short*)(ws + OFF_V);   // aliases vb
    unsigned short* outp = (unsigned short*)(ws + OFF_OP);

    float* out       = (float*)d_out;
    float* state_out = out + (size_t)BT * DIM;

    conv_x_kernel<<<16384, 256, 0, stream>>>(x, tmx, xx);
    conv_w_kernel<<<5120, 256, 0, stream>>>(Wk, Wv, Wr, Wg, Wo, wcat, wob);
    gemm256<0><<<1024, 512, 0, stream>>>(xx, wcat, nullptr,
                                         BT, 4096, 1024, kb, vb, rb, gb);
    chunk_fused<<<64 * NC, 256, 0, stream>>>(kb, vb, rb, gb, td, tf, ctru, outp);
    chunk_scan<<<1024, 256, 0, stream>>>(ctru, td, state_out);
    chunk_corr<<<64 * NC, 256, 0, stream>>>(kb, rb, gb, td, ctru, outp);
    gemm256<1><<<256, 512, 0, stream>>>(outp, wob, out,
                                        BT, 1024, 1024,
                                        nullptr, nullptr, nullptr, nullptr);
}